// Round 9
// baseline (135.192 us; speedup 1.0000x reference)
//
#include <hip/hip_runtime.h>

// Problem constants: B=8, N=16384, S=1024, T=2, D=3
#define NPTS 16384
#define SPTS 1024

typedef _Float16 half8 __attribute__((ext_vector_type(8)));
typedef float float16 __attribute__((ext_vector_type(16)));

union H8 { _Float16 h[8]; half8 v; uint4 q4; };

// min across each 32-lane half (validated r6/r7, absmax 0)
__device__ inline float wave32_min(float v) {
    v = fminf(v, __int_as_float(__builtin_amdgcn_mov_dpp(__float_as_int(v), 0xB1, 0xF, 0xF, true)));
    v = fminf(v, __int_as_float(__builtin_amdgcn_mov_dpp(__float_as_int(v), 0x4E, 0xF, 0xF, true)));
    v = fminf(v, __int_as_float(__builtin_amdgcn_mov_dpp(__float_as_int(v), 0x141, 0xF, 0xF, true)));
    v = fminf(v, __int_as_float(__builtin_amdgcn_mov_dpp(__float_as_int(v), 0x140, 0xF, 0xF, true)));
    v = fminf(v, __int_as_float(__builtin_amdgcn_ds_swizzle(__float_as_int(v), 0x401F)));
    return v;
}

// 3-way min shaped for LLVM's v_min3_f32 fusion (no inline asm: r9 hazard lesson).
__device__ inline float min3f(float a, float b, float c) {
    return fminf(fminf(a, b), c);
}

// r17. r16 counters: Occ 24% (not the predicted 35+), MfmaUtil 17, bank-conflicts
// 666K (staging), warm 56us vs ~13us arithmetic -> LDS round-trips + 16 col
// barriers are the latency. Insight: an MFMA A-frag is ONE point per lane
// (lanes>=32 zero) -> build it in REGISTERS from 3 coalesced per-lane global
// loads; no LDS write/read, no barrier, no block-wide staging redundancy.
//   col blocks [0,384):  64 sp; both sp B-frags in regs (built once); sweep 128
//                        gt A-tiles/wave from global; ZERO LDS / barriers in loop.
//   row blocks [384,768): 1024 gt rows; sp B-tiles in LDS (genuinely shared);
//                        gt A-frags from global regs. LDS 33.8->17KB.
// Uniform 256 MFMA/wave. RULES: (256,3) only (r8/r14 spill cliff); no inline asm
// on MFMA results (r9); 2 independent MFMAs in flight.

__global__ __launch_bounds__(256, 3) void fused_kernel(
    const float* __restrict__ gt,   // [8,16384,3]
    const float* __restrict__ sp,   // [8,1024,3]
    const float* __restrict__ tgt,  // [16,16384,3]
    const float* __restrict__ tsp,  // [16,1024,3]
    const float* __restrict__ tm,   // [2,3,3]
    unsigned int* __restrict__ counters,  // [0]=master
    float* __restrict__ partials,         // [768]
    float* __restrict__ out)
{
    const int bid = blockIdx.x;
    const int tid = threadIdx.x;
    const int lane = tid & 63;
    const int cl = lane & 31;
    const int w = tid >> 6;  // wave 0..3

    __shared__ uint4 s_frag4[1056];  // row pass: 32 sp B tiles (16.9 KB)
    __shared__ float cmerge[256];    // col pass: [wave][64] per-sp mins
    __shared__ float redbuf[4];
    __shared__ float redbufM[4];
    __shared__ int flag;

    float16 z16 = {0.f,0.f,0.f,0.f,0.f,0.f,0.f,0.f,0.f,0.f,0.f,0.f,0.f,0.f,0.f,0.f};

    if (bid < 384) {
        // ---- col pass: sp-side min (over gt). 64 sp/block, all-register operands ----
        int bb = bid >> 4;         // 24 batches
        int sc = bid & 15;         // 64-point sp chunk
        const float* spp = (bb < 8) ? sp + (size_t)bb * SPTS * 3
                                    : tsp + (size_t)(bb - 8) * SPTS * 3;
        const float* qp  = (bb < 8) ? gt + (size_t)bb * NPTS * 3
                                    : tgt + (size_t)(bb - 8) * NPTS * 3;

        // build both sp B-frags in registers (lane<32: col cl of tile; >=32: zero)
        H8 b0f, b1f;
        b0f.q4 = make_uint4(0, 0, 0, 0);
        b1f.q4 = make_uint4(0, 0, 0, 0);
        if (lane < 32) {
            const float* p0 = spp + (size_t)(sc * 64 + cl) * 3;
            float x = p0[0], y = p0[1], z = p0[2];
            b0f.h[0] = (_Float16)(-2.f * x); b0f.h[1] = (_Float16)(-2.f * y);
            b0f.h[2] = (_Float16)(-2.f * z); b0f.h[3] = (_Float16)1.f;
            b0f.h[4] = (_Float16)(x * x + y * y + z * z);
            const float* p1 = spp + (size_t)(sc * 64 + 32 + cl) * 3;
            x = p1[0]; y = p1[1]; z = p1[2];
            b1f.h[0] = (_Float16)(-2.f * x); b1f.h[1] = (_Float16)(-2.f * y);
            b1f.h[2] = (_Float16)(-2.f * z); b1f.h[3] = (_Float16)1.f;
            b1f.h[4] = (_Float16)(x * x + y * y + z * z);
        }

        float cm0 = 1e30f, cm1 = 1e30f;
        // wave w sweeps gt A-tiles [w*128, w*128+128)
        const float* qw = qp + (size_t)(w * 128) * 32 * 3;
        for (int at = 0; at < 128; at++) {
            H8 af; af.q4 = make_uint4(0, 0, 0, 0);
            if (lane < 32) {
                const float* gp = qw + (size_t)at * 96 + cl * 3;
                float x = gp[0], y = gp[1], z = gp[2];
                af.h[0] = (_Float16)x; af.h[1] = (_Float16)y; af.h[2] = (_Float16)z;
                af.h[3] = (_Float16)(x * x + y * y + z * z); af.h[4] = (_Float16)1.f;
            }
            float16 d0 = __builtin_amdgcn_mfma_f32_32x32x16_f16(af.v, b0f.v, z16, 0, 0, 0);
            float16 d1 = __builtin_amdgcn_mfma_f32_32x32x16_f16(af.v, b1f.v, z16, 0, 0, 0);
            // tree-min over this lane's 16 rows, accumulate per-col min
            {
                float g0 = min3f(d0[0],  d0[1],  d0[2]);
                float g1 = min3f(d0[3],  d0[4],  d0[5]);
                float g2 = min3f(d0[6],  d0[7],  d0[8]);
                float g3 = min3f(d0[9],  d0[10], d0[11]);
                float g4 = min3f(d0[12], d0[13], d0[14]);
                cm0 = min3f(cm0, min3f(g0, g1, g2), min3f(g3, fminf(g4, d0[15]), cm0));
            }
            {
                float g0 = min3f(d1[0],  d1[1],  d1[2]);
                float g1 = min3f(d1[3],  d1[4],  d1[5]);
                float g2 = min3f(d1[6],  d1[7],  d1[8]);
                float g3 = min3f(d1[9],  d1[10], d1[11]);
                float g4 = min3f(d1[12], d1[13], d1[14]);
                cm1 = min3f(cm1, min3f(g0, g1, g2), min3f(g3, fminf(g4, d1[15]), cm1));
            }
        }
        // merge lane halves (hi half covered rows 4..7,12..15,... of each tile)
        cm0 = fminf(cm0, __shfl_xor(cm0, 32, 64));
        cm1 = fminf(cm1, __shfl_xor(cm1, 32, 64));
        if (lane < 32) {
            cmerge[w * 64 + cl] = cm0;
            cmerge[w * 64 + 32 + cl] = cm1;
        }
        __syncthreads();
        if (tid < 64) {
            float v = fminf(fminf(cmerge[tid], cmerge[64 + tid]),
                            fminf(cmerge[128 + tid], cmerge[192 + tid]));
            float scale = (bb < 8) ? 1.f / (2.f * 3.f * 8.f * 1024.f)
                                   : 1.f / (2.f * 3.f * 16.f * 1024.f);
            float s = v * scale;
            for (int o = 32; o > 0; o >>= 1) s += __shfl_down(s, o, 64);
            if (tid == 0) partials[bid] = s;
        }
    } else {
        // ---- row pass: gt-side min (over sp). 1024 gt rows/block, A from regs ----
        int rbid = bid - 384;
        int bb = rbid >> 4;        // 24 batches
        int mc = rbid & 15;        // 1024-row gt chunk
        const float* spp = (bb < 8) ? sp + (size_t)bb * SPTS * 3
                                    : tsp + (size_t)(bb - 8) * SPTS * 3;
        const float* qp  = (bb < 8) ? gt + (size_t)bb * NPTS * 3
                                    : tgt + (size_t)(bb - 8) * NPTS * 3;

        // consistency-MSE prelude on row blocks 0..63 (1 point/thread)
        if (lane == 0) redbufM[w] = 0.f;
        if (rbid < 64) {
            int idx = rbid * 256 + tid;  // over (t,b,s) = 2*8*1024
            int t = idx >> 13;
            int bs = idx & 8191;
            const float* p = sp + (size_t)bs * 3;
            float x = p[0], y = p[1], z = p[2];
            const float* m = tm + t * 9;
            const float* q = tsp + (size_t)idx * 3;
            float mse = 0.f;
#pragma unroll
            for (int e = 0; e < 3; e++) {
                float v = fmaf(x, m[e], fmaf(y, m[3 + e], z * m[6 + e]));
                float d = v - q[e];
                mse = fmaf(d, d, mse);
            }
            for (int o = 32; o > 0; o >>= 1) mse += __shfl_down(mse, o, 64);
            if (lane == 0) redbufM[w] = mse;
        }

        // stage sp B-frags into LDS (shared by all 4 waves); zero slot per tile
        if (tid < 32) s_frag4[tid * 33 + 32] = make_uint4(0, 0, 0, 0);
        for (int i = tid; i < 1024; i += 256) {
            const float* pp = spp + (size_t)i * 3;
            float sx = pp[0], sy = pp[1], sz = pp[2];
            H8 bf; bf.q4 = make_uint4(0, 0, 0, 0);
            bf.h[0] = (_Float16)(-2.f * sx); bf.h[1] = (_Float16)(-2.f * sy);
            bf.h[2] = (_Float16)(-2.f * sz); bf.h[3] = (_Float16)1.f;
            bf.h[4] = (_Float16)(sx * sx + sy * sy + sz * sz);
            s_frag4[(i >> 5) * 33 + (i & 31)] = bf.q4;
        }
        __syncthreads();

        const char* lds = (const char*)s_frag4;
        const int laneoff = (lane < 32) ? cl * 16 : 512;
        const char* bBase = lds + laneoff;

        float wsum = 0.f;
        for (int mi = 0; mi < 8; mi++) {
            int mt = w * 8 + mi;  // this wave's m-tile (0..31)
            // build gt A-frag in regs: lane<32 holds row mc*1024 + mt*32 + cl
            H8 a; a.q4 = make_uint4(0, 0, 0, 0);
            if (lane < 32) {
                const float* gp = qp + (size_t)(mc * 1024 + mt * 32 + cl) * 3;
                float x = gp[0], y = gp[1], z = gp[2];
                a.h[0] = (_Float16)x; a.h[1] = (_Float16)y; a.h[2] = (_Float16)z;
                a.h[3] = (_Float16)(x * x + y * y + z * z); a.h[4] = (_Float16)1.f;
            }
            float rm[16];
#pragma unroll
            for (int r = 0; r < 16; r++) rm[r] = 1e30f;
#pragma unroll
            for (int t = 0; t < 32; t += 2) {
                H8 b0; b0.q4 = *(const uint4*)(bBase + t * 528);
                H8 b1; b1.q4 = *(const uint4*)(bBase + (t + 1) * 528);
                float16 d0 = __builtin_amdgcn_mfma_f32_32x32x16_f16(a.v, b0.v, z16, 0, 0, 0);
                float16 d1 = __builtin_amdgcn_mfma_f32_32x32x16_f16(a.v, b1.v, z16, 0, 0, 0);
#pragma unroll
                for (int r = 0; r < 16; r++) rm[r] = min3f(rm[r], d0[r], d1[r]);
            }
            float tsum = 0.f;
#pragma unroll
            for (int r = 0; r < 16; r++) tsum += wave32_min(rm[r]);
            wsum += tsum;
        }
        wsum += __shfl_xor(wsum, 32, 64);
        if (lane == 0) redbuf[w] = wsum;
        __syncthreads();
        if (tid == 0) {
            float scale = (bb < 8) ? 1.f / (2.f * 3.f * 8.f * 16384.f)
                                   : 1.f / (2.f * 3.f * 16.f * 16384.f);
            partials[bid] = (redbuf[0] + redbuf[1] + redbuf[2] + redbuf[3]) * scale
                          + (redbufM[0] + redbufM[1] + redbufM[2] + redbufM[3])
                            * (1000.f / (2.f * 8.f * 1024.f * 3.f));
        }
    }

    // ---------------- master counter: last block sums all partials -> out ----------------
    __syncthreads();
    if (tid == 0) {
        __threadfence();
        unsigned int old = atomicAdd(&counters[0], 1u);
        flag = (old == 767u);
    }
    __syncthreads();
    if (flag) {
        __threadfence();
        float s2 = 0.f;
        for (int i = tid; i < 768; i += 256) s2 += partials[i];
        for (int o = 32; o > 0; o >>= 1) s2 += __shfl_down(s2, o, 64);
        if (lane == 0) redbuf[w] = s2;
        __syncthreads();
        if (tid == 0) out[0] = redbuf[0] + redbuf[1] + redbuf[2] + redbuf[3];
    }
}

extern "C" void kernel_launch(void* const* d_in, const int* in_sizes, int n_in,
                              void* d_out, int out_size, void* d_ws, size_t ws_size,
                              hipStream_t stream) {
    const float* gt  = (const float*)d_in[0];  // gt_points [8,16384,3]
    const float* sp  = (const float*)d_in[1];  // structure_points [8,1024,3]
    const float* tgt = (const float*)d_in[2];  // transed_gt_points [2,8,16384,3]
    const float* tsp = (const float*)d_in[3];  // transed_structure_points [2,8,1024,3]
    const float* tm  = (const float*)d_in[4];  // trans_mats [2,3,3]

    unsigned int* counters = (unsigned int*)d_ws;
    float* partials = (float*)((char*)d_ws + 64);  // 768 floats

    hipMemsetAsync(d_ws, 0, 64, stream);  // master counter

    fused_kernel<<<768, 256, 0, stream>>>(gt, sp, tgt, tsp, tm, counters, partials,
                                          (float*)d_out);
}

// Round 10
// 119.257 us; speedup vs baseline: 1.1336x; 1.1336x over previous
//
#include <hip/hip_runtime.h>

// Problem constants: B=8, N=16384, S=1024, T=2, D=3
#define NPTS 16384
#define SPTS 1024

typedef _Float16 half8 __attribute__((ext_vector_type(8)));
typedef float float16 __attribute__((ext_vector_type(16)));

union H8 { _Float16 h[8]; half8 v; uint4 q4; };

// min across each 32-lane half (validated r6/r7, absmax 0)
__device__ inline float wave32_min(float v) {
    v = fminf(v, __int_as_float(__builtin_amdgcn_mov_dpp(__float_as_int(v), 0xB1, 0xF, 0xF, true)));
    v = fminf(v, __int_as_float(__builtin_amdgcn_mov_dpp(__float_as_int(v), 0x4E, 0xF, 0xF, true)));
    v = fminf(v, __int_as_float(__builtin_amdgcn_mov_dpp(__float_as_int(v), 0x141, 0xF, 0xF, true)));
    v = fminf(v, __int_as_float(__builtin_amdgcn_mov_dpp(__float_as_int(v), 0x140, 0xF, 0xF, true)));
    v = fminf(v, __int_as_float(__builtin_amdgcn_ds_swizzle(__float_as_int(v), 0x401F)));
    return v;
}

// 3-way min shaped for LLVM's v_min3_f32 fusion (no inline asm: r9 hazard lesson).
__device__ inline float min3f(float a, float b, float c) {
    return fminf(fminf(a, b), c);
}

// r18. r17 lesson: per-lane scalar global A-frags regressed (56->76us): load->cvt
// ->MFMA serial chain, VALUBusy 29 / MfmaUtil 13. LDS staging (r16) is right.
// r16's remaining costs: (a) staging used 12 SCALAR loads per 4 points (G13
// violation), (b) col pass staged gt 16x per bb, (c) rigid 768-block grid ->
// Occ 24% (imbalance tail). Fixes:
//   - stage4<>: 4 points = 48B = 3 x uint4 loads per thread (loads / 4).
//   - col: 192 blocks x 128 sp (4 A-tiles; wave owns 1, sweeps all 32 B-tiles
//     per round; 512 MFMA/wave); gt staged 8x/bb (was 16x). Dispatched FIRST.
//   - row: 768 blocks x 512 rows (128 MFMA/wave, light) backfill around col
//     poles. Grid 960. MSE prelude in row blocks 0..63.
// RULES: (256,3) only (r8/r14 spill cliff at (256,4)); no inline asm on MFMA
// results (r9); 2-deep MFMA; plain stores + master completion counter.

__device__ inline uint4 make_bfrag(float x, float y, float z) {
    H8 f; f.q4 = make_uint4(0, 0, 0, 0);
    f.h[0] = (_Float16)(-2.f * x); f.h[1] = (_Float16)(-2.f * y);
    f.h[2] = (_Float16)(-2.f * z); f.h[3] = (_Float16)1.f;
    f.h[4] = (_Float16)(x * x + y * y + z * z);
    return f.q4;
}
__device__ inline uint4 make_afrag(float x, float y, float z) {
    H8 f; f.q4 = make_uint4(0, 0, 0, 0);
    f.h[0] = (_Float16)x; f.h[1] = (_Float16)y; f.h[2] = (_Float16)z;
    f.h[3] = (_Float16)(x * x + y * y + z * z); f.h[4] = (_Float16)1.f;
    return f.q4;
}

// thread-slot i stages points 4i..4i+3 (48B = 3 uint4) into 33-stride frag LDS
template <bool BFORM>
__device__ inline void stage4(uint4* __restrict__ dst, const uint4* __restrict__ src4, int i) {
    uint4 u0 = src4[3 * i], u1 = src4[3 * i + 1], u2 = src4[3 * i + 2];
    float px[4] = {__uint_as_float(u0.x), __uint_as_float(u0.w),
                   __uint_as_float(u1.z), __uint_as_float(u2.y)};
    float py[4] = {__uint_as_float(u0.y), __uint_as_float(u1.x),
                   __uint_as_float(u1.w), __uint_as_float(u2.z)};
    float pz[4] = {__uint_as_float(u0.z), __uint_as_float(u1.y),
                   __uint_as_float(u2.x), __uint_as_float(u2.w)};
#pragma unroll
    for (int k = 0; k < 4; k++) {
        int p = 4 * i + k;
        dst[(p >> 5) * 33 + (p & 31)] =
            BFORM ? make_bfrag(px[k], py[k], pz[k]) : make_afrag(px[k], py[k], pz[k]);
    }
}

__global__ __launch_bounds__(256, 3) void fused_kernel(
    const float* __restrict__ gt,   // [8,16384,3]
    const float* __restrict__ sp,   // [8,1024,3]
    const float* __restrict__ tgt,  // [16,16384,3]
    const float* __restrict__ tsp,  // [16,1024,3]
    const float* __restrict__ tm,   // [2,3,3]
    unsigned int* __restrict__ counters,  // [0]=master
    float* __restrict__ partials,         // [960]
    float* __restrict__ out)
{
    const int bid = blockIdx.x;
    const int tid = threadIdx.x;
    const int lane = tid & 63;
    const int cl = lane & 31;
    const int w = tid >> 6;  // wave 0..3

    // col: B dbuf [0,1056)+[1056,2112), A 4 tiles [2112,2244)  (35.9 KB)
    // row: B sp [0,1056), A gt 16 tiles [1056,1584)
    __shared__ uint4 s_frag4[2244];
    __shared__ float cmerge[128];
    __shared__ float redbuf[4];
    __shared__ float redbufM[4];
    __shared__ int flag;

    float16 z16 = {0.f,0.f,0.f,0.f,0.f,0.f,0.f,0.f,0.f,0.f,0.f,0.f,0.f,0.f,0.f,0.f};

    if (bid < 192) {
        // ---- col pass: sp-side min (over gt). 128 sp/block, dbuf gt staging ----
        int bb = bid >> 3;         // 24 batches
        int sc = bid & 7;          // 128-point sp chunk
        const float* spp = (bb < 8) ? sp + (size_t)bb * SPTS * 3
                                    : tsp + (size_t)(bb - 8) * SPTS * 3;
        const float* qp  = (bb < 8) ? gt + (size_t)bb * NPTS * 3
                                    : tgt + (size_t)(bb - 8) * NPTS * 3;

        // zero slots: 64 B tiles (both buffers) + 4 A tiles
        if (tid < 64) s_frag4[(tid >> 5) * 1056 + (tid & 31) * 33 + 32] = make_uint4(0, 0, 0, 0);
        else if (tid < 68) s_frag4[2112 + (tid - 64) * 33 + 32] = make_uint4(0, 0, 0, 0);
        // stage A: 128 sp points (96 uint4), threads 0..31 x 4 points
        if (tid < 32)
            stage4<false>(s_frag4 + 2112, (const uint4*)(spp) + (size_t)sc * 96, tid);
        // prologue: stage gt round 0 into buf0 (768 uint4, 4 pts/thread)
        stage4<true>(s_frag4, (const uint4*)qp, tid);
        __syncthreads();

        const char* lds = (const char*)s_frag4;
        const int laneoff = (lane < 32) ? cl * 16 : 512;
        H8 a; a.q4 = *(const uint4*)(lds + 2112 * 16 + laneoff + w * 528);

        float rm[16];
#pragma unroll
        for (int r = 0; r < 16; r++) rm[r] = 1e30f;

        for (int g = 0; g < 16; g++) {
            int cur = g & 1;
            // stage g+1 into other buffer (overlaps compute below)
            if (g < 15)
                stage4<true>(s_frag4 + (cur ^ 1) * 1056,
                             (const uint4*)qp + (size_t)(g + 1) * 768, tid);
            // compute on buf[cur]: all 32 B tiles, this wave's A tile
            const char* bBase = lds + cur * 1056 * 16 + laneoff;
#pragma unroll
            for (int j = 0; j < 32; j += 2) {
                H8 b0; b0.q4 = *(const uint4*)(bBase + j * 528);
                H8 b1; b1.q4 = *(const uint4*)(bBase + (j + 1) * 528);
                float16 d0 = __builtin_amdgcn_mfma_f32_32x32x16_f16(a.v, b0.v, z16, 0, 0, 0);
                float16 d1 = __builtin_amdgcn_mfma_f32_32x32x16_f16(a.v, b1.v, z16, 0, 0, 0);
#pragma unroll
                for (int r = 0; r < 16; r++) rm[r] = min3f(rm[r], d0[r], d1[r]);
            }
            __syncthreads();  // staging of g+1 done; buf[cur] reusable
        }
        // wave-local: min over 32 gt cols per row; rows are wave-private sp points
#pragma unroll
        for (int r = 0; r < 16; r++) {
            float wm = wave32_min(rm[r]);
            if (cl == 0)
                cmerge[w * 32 + (r & 3) + 8 * (r >> 2) + 4 * (lane >> 5)] = wm;
        }
        __syncthreads();
        if (tid < 64) {
            float scale = (bb < 8) ? 1.f / (2.f * 3.f * 8.f * 1024.f)
                                   : 1.f / (2.f * 3.f * 16.f * 1024.f);
            float s = (cmerge[tid] + cmerge[64 + tid]) * scale;
            for (int o = 32; o > 0; o >>= 1) s += __shfl_down(s, o, 64);
            if (tid == 0) partials[bid] = s;
        }
    } else {
        // ---- row pass: gt-side min (over sp). 768 blocks x 512 gt rows ----
        int rbid = bid - 192;
        int bb = rbid >> 5;        // 24 batches
        int mc = rbid & 31;        // 512-row gt chunk
        const float* spp = (bb < 8) ? sp + (size_t)bb * SPTS * 3
                                    : tsp + (size_t)(bb - 8) * SPTS * 3;
        const float* qp  = (bb < 8) ? gt + (size_t)bb * NPTS * 3
                                    : tgt + (size_t)(bb - 8) * NPTS * 3;

        // consistency-MSE prelude on row blocks 0..63 (1 point/thread)
        if (lane == 0) redbufM[w] = 0.f;
        if (rbid < 64) {
            int idx = rbid * 256 + tid;  // over (t,b,s) = 2*8*1024
            int t = idx >> 13;
            int bs = idx & 8191;
            const float* p = sp + (size_t)bs * 3;
            float x = p[0], y = p[1], z = p[2];
            const float* m = tm + t * 9;
            const float* q = tsp + (size_t)idx * 3;
            float mse = 0.f;
#pragma unroll
            for (int e = 0; e < 3; e++) {
                float v = fmaf(x, m[e], fmaf(y, m[3 + e], z * m[6 + e]));
                float d = v - q[e];
                mse = fmaf(d, d, mse);
            }
            for (int o = 32; o > 0; o >>= 1) mse += __shfl_down(mse, o, 64);
            if (lane == 0) redbufM[w] = mse;
        }

        // zero slots: 32 sp B tiles + 16 gt A tiles
        if (tid < 32) s_frag4[tid * 33 + 32] = make_uint4(0, 0, 0, 0);
        else if (tid < 48) s_frag4[1056 + (tid - 32) * 33 + 32] = make_uint4(0, 0, 0, 0);
        // stage sp B (1024 pts, 4/thread) + gt A (512 pts, threads 0..127 x 4)
        stage4<true>(s_frag4, (const uint4*)spp, tid);
        if (tid < 128)
            stage4<false>(s_frag4 + 1056, (const uint4*)qp + (size_t)mc * 384, tid);
        __syncthreads();

        const char* lds = (const char*)s_frag4;
        const int laneoff = (lane < 32) ? cl * 16 : 512;
        const char* bBase = lds + laneoff;
        const char* aBase = lds + 1056 * 16 + laneoff;

        float wsum = 0.f;
        for (int mi = 0; mi < 4; mi++) {
            int mt = w * 4 + mi;  // this wave's m-tile (0..15)
            H8 a; a.q4 = *(const uint4*)(aBase + mt * 528);
            float rm[16];
#pragma unroll
            for (int r = 0; r < 16; r++) rm[r] = 1e30f;
#pragma unroll
            for (int t = 0; t < 32; t += 2) {
                H8 b0; b0.q4 = *(const uint4*)(bBase + t * 528);
                H8 b1; b1.q4 = *(const uint4*)(bBase + (t + 1) * 528);
                float16 d0 = __builtin_amdgcn_mfma_f32_32x32x16_f16(a.v, b0.v, z16, 0, 0, 0);
                float16 d1 = __builtin_amdgcn_mfma_f32_32x32x16_f16(a.v, b1.v, z16, 0, 0, 0);
#pragma unroll
                for (int r = 0; r < 16; r++) rm[r] = min3f(rm[r], d0[r], d1[r]);
            }
            float tsum = 0.f;
#pragma unroll
            for (int r = 0; r < 16; r++) tsum += wave32_min(rm[r]);
            wsum += tsum;
        }
        wsum += __shfl_xor(wsum, 32, 64);
        if (lane == 0) redbuf[w] = wsum;
        __syncthreads();
        if (tid == 0) {
            float scale = (bb < 8) ? 1.f / (2.f * 3.f * 8.f * 16384.f)
                                   : 1.f / (2.f * 3.f * 16.f * 16384.f);
            partials[bid] = (redbuf[0] + redbuf[1] + redbuf[2] + redbuf[3]) * scale
                          + (redbufM[0] + redbufM[1] + redbufM[2] + redbufM[3])
                            * (1000.f / (2.f * 8.f * 1024.f * 3.f));
        }
    }

    // ---------------- master counter: last block sums all partials -> out ----------------
    __syncthreads();
    if (tid == 0) {
        __threadfence();
        unsigned int old = atomicAdd(&counters[0], 1u);
        flag = (old == 959u);
    }
    __syncthreads();
    if (flag) {
        __threadfence();
        float s2 = 0.f;
        for (int i = tid; i < 960; i += 256) s2 += partials[i];
        for (int o = 32; o > 0; o >>= 1) s2 += __shfl_down(s2, o, 64);
        if (lane == 0) redbuf[w] = s2;
        __syncthreads();
        if (tid == 0) out[0] = redbuf[0] + redbuf[1] + redbuf[2] + redbuf[3];
    }
}

extern "C" void kernel_launch(void* const* d_in, const int* in_sizes, int n_in,
                              void* d_out, int out_size, void* d_ws, size_t ws_size,
                              hipStream_t stream) {
    const float* gt  = (const float*)d_in[0];  // gt_points [8,16384,3]
    const float* sp  = (const float*)d_in[1];  // structure_points [8,1024,3]
    const float* tgt = (const float*)d_in[2];  // transed_gt_points [2,8,16384,3]
    const float* tsp = (const float*)d_in[3];  // transed_structure_points [2,8,1024,3]
    const float* tm  = (const float*)d_in[4];  // trans_mats [2,3,3]

    unsigned int* counters = (unsigned int*)d_ws;
    float* partials = (float*)((char*)d_ws + 64);  // 960 floats

    hipMemsetAsync(d_ws, 0, 64, stream);  // master counter

    fused_kernel<<<960, 256, 0, stream>>>(gt, sp, tgt, tsp, tm, counters, partials,
                                          (float*)d_out);
}